// Round 1
// baseline (495.240 us; speedup 1.0000x reference)
//
#include <hip/hip_runtime.h>

// ---------------------------------------------------------------- constants
#define TTOK 32768
#define DM   256
#define NF   1024
#define KMAX 32

typedef __attribute__((ext_vector_type(8))) unsigned short ushort8;
typedef __attribute__((ext_vector_type(8))) __bf16 bf16x8;
typedef __attribute__((ext_vector_type(4))) float floatx4;

// workspace offsets (all 256B aligned)
constexpr size_t O_SLOT = 0;                                   // 1 uint (max|Wt|)
constexpr size_t O_S    = 256;                                 // 1024 f32 sigmoid(alpha)
constexpr size_t O_WCT  = O_S    + 4096;                       // Wc^T  [1024][256] bf16
constexpr size_t O_WGT  = O_WCT  + (size_t)NF*DM*2;            // Wg^T  [1024][256] bf16
constexpr size_t O_WDT  = O_WGT  + (size_t)NF*DM*2;            // Wd^T  [256][1024] bf16
constexpr size_t O_WTT  = O_WDT  + (size_t)DM*NF*2;            // Wt^T  [256][1024] f32
constexpr size_t O_XBF  = O_WTT  + (size_t)DM*NF*4;            // x bf16 [T][256]
constexpr size_t O_CNT  = O_XBF  + (size_t)TTOK*DM*2;          // counts [T]
constexpr size_t O_CIDX = O_CNT  + (size_t)TTOK*4;             // cand d (raw) [T][KMAX]
constexpr size_t O_CVAL = O_CIDX + (size_t)TTOK*KMAX*4;        // cand val [T][KMAX]
constexpr size_t O_FUSD = O_CVAL + (size_t)TTOK*KMAX*4;        // fused bf16 [T][1024]

__device__ __forceinline__ float bf2f(unsigned short u) {
    union { unsigned int i; float f; } c; c.i = ((unsigned int)u) << 16; return c.f;
}
__device__ __forceinline__ unsigned short f2bf(float v) {
    union { float f; unsigned int i; } c; c.f = v;
    unsigned int b = c.i;
    return (unsigned short)((b + 0x7FFFu + ((b >> 16) & 1u)) >> 16);
}
__device__ __forceinline__ float sigm(float z) { return 1.0f / (1.0f + __expf(-z)); }
// tanh-gelu: max |diff| vs exact erf-gelu ~3e-3, far under tolerance
__device__ __forceinline__ float gelu_f(float x) {
    return x * sigm(1.59576912f * (x + 0.044715f * x * x * x));
}
// async global->LDS, 16B per lane; lds dest = wave-uniform base + lane*16 [m97/m104]
__device__ __forceinline__ void g2lds16(const unsigned short* g, unsigned short* l) {
    __builtin_amdgcn_global_load_lds((const __attribute__((address_space(1))) unsigned int*)g,
                                     (__attribute__((address_space(3))) unsigned int*)l, 16, 0, 0);
}

// ------------------------------------------------- kernel 1: pack weights
__global__ void pack_kernel(const float* __restrict__ Wt, const float* __restrict__ alpha,
                            const float* __restrict__ Wc, const float* __restrict__ Wg,
                            const float* __restrict__ Wd,
                            unsigned short* __restrict__ Wct, unsigned short* __restrict__ Wgt,
                            unsigned short* __restrict__ WdT, float* __restrict__ WtT,
                            float* __restrict__ s, unsigned int* __restrict__ slot) {
    int e = blockIdx.x * 256 + threadIdx.x;
    if (e == 0) *slot = 0u;
    { int f = e >> 8, k = e & 255;           // Wc/Wg are [256][1024]
      Wct[e] = f2bf(Wc[k * NF + f]);
      Wgt[e] = f2bf(Wg[k * NF + f]); }
    { int n = e >> 10, k = e & 1023;         // Wd is [1024][256]
      WdT[e] = f2bf(Wd[k * DM + n]); }
    { int d = e >> 10, f = e & 1023;         // Wt is [1024][256]
      WtT[e] = Wt[f * DM + d]; }
    if (e < NF) s[e] = sigm(alpha[e]);
}

// ------------------------------------------------- kernel 2: max|Wt| reduce
__global__ void minmax_kernel(const float* __restrict__ Wt, unsigned int* __restrict__ slot) {
    int g = blockIdx.x * 256 + threadIdx.x;
    float lm = 0.0f;
    for (int i = g; i < NF * DM; i += 128 * 256) lm = fmaxf(lm, fabsf(Wt[i]));
    #pragma unroll
    for (int o = 32; o > 0; o >>= 1) lm = fmaxf(lm, __shfl_xor(lm, o));
    if ((threadIdx.x & 63) == 0) atomicMax(slot, __float_as_uint(lm)); // |w|>=0: uint order ok
}

// ------------------------------------------------- kernel 3: candidates + x->bf16
__global__ void cand_kernel(const float* __restrict__ x, const unsigned int* __restrict__ slot,
                            unsigned short* __restrict__ xbf, int* __restrict__ counts,
                            int* __restrict__ cidx, float* __restrict__ cval) {
    int i = blockIdx.x, t = threadIdx.x;
    float v = x[i * DM + t];
    xbf[i * DM + t] = f2bf(v);
    float m = v;
    #pragma unroll
    for (int o = 32; o > 0; o >>= 1) m = fmaxf(m, __shfl_xor(m, o));
    __shared__ float wm[4];
    __shared__ int cnt;
    __shared__ int sidx[KMAX];
    __shared__ float sval[KMAX];
    if ((t & 63) == 0) wm[t >> 6] = m;
    if (t == 0) cnt = 0;
    __syncthreads();
    float xmax = fmaxf(fmaxf(wm[0], wm[1]), fmaxf(wm[2], wm[3]));
    float delta = 2.0f * __uint_as_float(*slot);   // >= Wmax - Wmin : exact exclusion bound
    float thr = xmax - delta;
    if (v >= thr) {
        int p = atomicAdd(&cnt, 1);
        if (p < KMAX) { sidx[p] = t; sval[p] = v; }   // raw d index
    }
    __syncthreads();
    int c = cnt;
    if (t == 0) counts[i] = c;
    if (t < (c < KMAX ? c : KMAX)) {
        cidx[i * KMAX + t] = sidx[t];
        cval[i * KMAX + t] = sval[t];
    }
}

// ------------------------------------------------- kernel 4: fused GEMM1
// (x@Wc, x@Wg) MFMA + tropical max-plus + convex/concave + gate blend.
// r7 restructure: occupancy was register-ceiling-bound (acc 64 f32 + frags
// -> ~128 unified regs -> 4 waves/SIMD = 16 waves/CU; LDS 2-block cap hit the
// SAME 16, so LDS diet alone was free-lunch-less). New shape:
//  - 128x64 tile, 8 waves of 32x32 -> acc 32 regs, K-loop peak ~70,
//    __launch_bounds__(512,6) targets 6 waves/SIMD = 24 waves/CU (75%).
//  - sOV candidate cache KMAX->KCAP=12 (P(count>12)~1e-4; exact 256-d
//    fallback covers the tail), staged at kernel start (overlaps K-loop).
//  - per-wave 1KB obuf regions, quad-XOR chunk swizzle (2-way banks = free),
//    per-mi ushort8 cooperative store -> no cross-wave barrier, 8KB total.
//  - LDS 31744B (5 blocks worth; occupancy now register-gated as intended).
//  - XCD swizzle: 16 bfb-siblings of a bm consecutive per XCD (A-tile+meta
//    L2-hot, r6 lesson).
#define LDSS  32   // ushorts per LDS row (wave-uniform-base DMA, m104: no pad)
#define KCAP  12
#define KPADL 13
__global__ __launch_bounds__(512, 6) void gemm1_kernel(
    const unsigned short* __restrict__ A,   // xbf [T][256]
    const unsigned short* __restrict__ Bct, // [1024][256]
    const unsigned short* __restrict__ Bgt, // [1024][256]
    const float* __restrict__ bc, const float* __restrict__ bg,
    const int* __restrict__ counts, const int* __restrict__ cidx,
    const float* __restrict__ cval, const float* __restrict__ x,
    const float* __restrict__ WtT, const float* __restrict__ bt,
    const float* __restrict__ slx, const float* __restrict__ ofx,
    const float* __restrict__ slc, const float* __restrict__ ofc,
    const float* __restrict__ s, unsigned short* __restrict__ fused) {
    __shared__ __align__(16) char smem[31744];
    unsigned short* As  = (unsigned short*)smem;            // [0,8K)     128x32
    unsigned short* Bcs = As + 4096;                        // [8K,12K)    64x32
    unsigned short* Bgs = As + 6144;                        // [12K,16K)   64x32
    float* par = (float*)smem;                              // [0,9216) epilogue overlay
    unsigned short* obuf = (unsigned short*)(smem + 16384); // [16K,24K) 8 waves x 1KB
    int* sOV  = (int*)(smem + 24576);                       // [24K,+6656) 128 x KPADL
    int* sCnt = (int*)(smem + 31232);                       // 512B
    const int t = threadIdx.x;
    // XCD-aware swizzle (speed heuristic only; correctness order-free)
    const int b = blockIdx.x;
    const int xcd = b & 7, j = b >> 3;
    const int bfb = j & 15;                 // f-block (64 cols), siblings consecutive
    const int bm  = (j >> 4) * 8 + xcd;     // m-block (128 rows)
    const int wave = t >> 6, lane = t & 63;
    const int wm = wave >> 1, wf = wave & 1;   // 4 M-waves x 2 F-waves, 32x32 each
    const int lr = lane & 15, quad = lane >> 4;

    // ---- stage candidate meta early (disjoint from K-loop staging region;
    //      first K-loop barrier publishes it). Pre-padded: d=0, val=-1e30.
    if (t < 128) sCnt[t] = counts[bm * 128 + t];
    const int PADV = (int)(((unsigned int)f2bf(-1e30f)) << 16);
    for (int e = t; e < 2048; e += 512) {
        int m = e >> 4, k = e & 15;
        if (k < KCAP) {
            int c = counts[bm * 128 + m];
            int pk = PADV;
            if (k < (c < KCAP ? c : KCAP)) {
                int d  = cidx[(size_t)(bm * 128 + m) * KMAX + k];
                float v = cval[(size_t)(bm * 128 + m) * KMAX + k];
                pk = (int)(((unsigned int)f2bf(v)) << 16) | d;
            }
            sOV[m * KPADL + k] = pk;
        }
    }

    // ---- staging roles: waves 0-3 -> A (32 rows each), 4-5 -> Bc, 6-7 -> Bg
    const unsigned short* gbase;
    unsigned short* lbase;
    if (wave < 4)      { gbase = A   + (size_t)(bm * 128 + wave * 32) * DM;       lbase = &As[wave * 32 * LDSS]; }
    else if (wave < 6) { gbase = Bct + (size_t)(bfb * 64 + (wave - 4) * 32) * DM; lbase = &Bcs[(wave - 4) * 32 * LDSS]; }
    else               { gbase = Bgt + (size_t)(bfb * 64 + (wave - 6) * 32) * DM; lbase = &Bgs[(wave - 6) * 32 * LDSS]; }
    const unsigned short* g0 = gbase + (size_t)(lane >> 2) * DM + ((lane & 3) << 3);

    floatx4 accc[2][2], accg[2][2];
    #pragma unroll
    for (int i = 0; i < 2; i++)
        #pragma unroll
        for (int jj = 0; jj < 2; jj++) { accc[i][jj] = (floatx4)0.0f; accg[i][jj] = (floatx4)0.0f; }

    for (int k0 = 0; k0 < DM; k0 += 32) {
        __syncthreads();            // covers sOV/sCnt stage (1st iter) + prior ds_reads
        g2lds16(g0 + k0, lbase);                       // rows [0,16) of this wave's 32
        g2lds16(g0 + 16 * DM + k0, lbase + 16 * LDSS); // rows [16,32)
        __syncthreads();
        bf16x8 af[2], bcf[2], bgf[2];
        #pragma unroll
        for (int mi = 0; mi < 2; mi++)
            af[mi] = *(const bf16x8*)&As[(wm * 32 + mi * 16 + lr) * LDSS + quad * 8];
        #pragma unroll
        for (int ni = 0; ni < 2; ni++) {
            bcf[ni] = *(const bf16x8*)&Bcs[(wf * 32 + ni * 16 + lr) * LDSS + quad * 8];
            bgf[ni] = *(const bf16x8*)&Bgs[(wf * 32 + ni * 16 + lr) * LDSS + quad * 8];
        }
        #pragma unroll
        for (int mi = 0; mi < 2; mi++)
            #pragma unroll
            for (int ni = 0; ni < 2; ni++) {
                accc[mi][ni] = __builtin_amdgcn_mfma_f32_16x16x32_bf16(af[mi], bcf[ni], accc[mi][ni], 0, 0, 0);
                accg[mi][ni] = __builtin_amdgcn_mfma_f32_16x16x32_bf16(af[mi], bgf[ni], accg[mi][ni], 0, 0, 0);
            }
    }
    __syncthreads();   // staging bufs dead; overlay par

    // ---- stage epilogue params into LDS: par[fl*36 + {0..7 slx, 8..15 ofx,
    //      16..23 slc, 24..31 ofc, 32 bt, 33 s, 34 bc, 35 bg}], fl in [0,64)
    { int ff = t >> 3, w = t & 7;                 // 512 threads == 64*8 exactly
      int gf = (bfb * 64 + ff) * 8 + w;
      par[ff * 36 + w]      = slx[gf];
      par[ff * 36 + 8 + w]  = ofx[gf];
      par[ff * 36 + 16 + w] = slc[gf];
      par[ff * 36 + 24 + w] = ofc[gf]; }
    if (t < 64) {
        int gf = bfb * 64 + t;
        par[t * 36 + 32] = bt[gf];
        par[t * 36 + 33] = s[gf];
        par[t * 36 + 34] = bc[gf];
        par[t * 36 + 35] = bg[gf];
    }
    __syncthreads();

    // ---- fused epilogue: tropical z + convex/concave + gate blend ----
    // C/D layout col=lane&15, row=quad*4+r  [verified m89/m91]
    const int f0 = bfb * 64 + wf * 32 + lr;    // ni=0 global f; ni=1 is +16
    unsigned short* owave = obuf + wave * 512;  // 16 rows x 32 cols, quad-XOR chunks
    #pragma unroll
    for (int mi = 0; mi < 2; mi++) {
        const int mb = wm * 32 + mi * 16 + quad * 4;   // local m of r=0
        int c0 = sCnt[mb], c1 = sCnt[mb + 1], c2 = sCnt[mb + 2], c3 = sCnt[mb + 3];
        int k0c = c0 < KCAP ? c0 : KCAP, k1c = c1 < KCAP ? c1 : KCAP;
        int k2c = c2 < KCAP ? c2 : KCAP, k3c = c3 < KCAP ? c3 : KCAP;
        int km = max(max(k0c, k1c), max(k2c, k3c));
        float z0a = -1e30f, z1a = -1e30f, z2a = -1e30f, z3a = -1e30f;  // ni=0
        float z0b = -1e30f, z1b = -1e30f, z2b = -1e30f, z3b = -1e30f;  // ni=1
        for (int k = 0; k < km; k++) {
            int p0 = sOV[(mb + 0) * KPADL + k];
            int p1 = sOV[(mb + 1) * KPADL + k];
            int p2 = sOV[(mb + 2) * KPADL + k];
            int p3 = sOV[(mb + 3) * KPADL + k];
            const float* r0 = WtT + ((p0 & 0xFFFF) << 10) + f0;
            const float* r1 = WtT + ((p1 & 0xFFFF) << 10) + f0;
            const float* r2 = WtT + ((p2 & 0xFFFF) << 10) + f0;
            const float* r3 = WtT + ((p3 & 0xFFFF) << 10) + f0;
            float w0a = r0[0], w0b = r0[16];
            float w1a = r1[0], w1b = r1[16];
            float w2a = r2[0], w2b = r2[16];
            float w3a = r3[0], w3b = r3[16];
            float v0 = __int_as_float(p0 & 0xFFFF0000);
            float v1 = __int_as_float(p1 & 0xFFFF0000);
            float v2 = __int_as_float(p2 & 0xFFFF0000);
            float v3 = __int_as_float(p3 & 0xFFFF0000);
            z0a = fmaxf(z0a, v0 + w0a); z0b = fmaxf(z0b, v0 + w0b);
            z1a = fmaxf(z1a, v1 + w1a); z1b = fmaxf(z1b, v1 + w1b);
            z2a = fmaxf(z2a, v2 + w2a); z2b = fmaxf(z2b, v2 + w2b);
            z3a = fmaxf(z3a, v3 + w3a); z3b = fmaxf(z3b, v3 + w3b);
        }
        // exact fallback (count > KCAP, ~1e-4 of rows): full 256-d scan
        if (c0 > KCAP || c1 > KCAP || c2 > KCAP || c3 > KCAP) {
            float za[4] = { z0a, z1a, z2a, z3a };
            float zb[4] = { z0b, z1b, z2b, z3b };
            int cc[4] = { c0, c1, c2, c3 };
            #pragma unroll 1
            for (int r = 0; r < 4; r++) if (cc[r] > KCAP) {
                const float* xr = x + (size_t)(bm * 128 + mb + r) * DM;
                float ma = -1e30f, mbv = -1e30f;
                for (int d = 0; d < DM; d++) {
                    float xv = xr[d];
                    ma  = fmaxf(ma,  xv + WtT[d * NF + f0]);
                    mbv = fmaxf(mbv, xv + WtT[d * NF + f0 + 16]);
                }
                za[r] = ma; zb[r] = mbv;
            }
            z0a = za[0]; z1a = za[1]; z2a = za[2]; z3a = za[3];
            z0b = zb[0]; z1b = zb[1]; z2b = zb[2]; z3b = zb[3];
        }
        #pragma unroll
        for (int ni = 0; ni < 2; ni++) {
            const int fl = wf * 32 + ni * 16 + lr;
            const float* pp = par + fl * 36;
            float4 a0 = *(const float4*)(pp),      a1 = *(const float4*)(pp + 4);
            float4 b0 = *(const float4*)(pp + 8),  b1 = *(const float4*)(pp + 12);
            float4 cc0 = *(const float4*)(pp + 16), cc1 = *(const float4*)(pp + 20);
            float4 d0 = *(const float4*)(pp + 24), d1 = *(const float4*)(pp + 28);
            float4 sc = *(const float4*)(pp + 32);  // bt, s, bc, bg
            float zr[4];
            if (ni == 0) { zr[0] = z0a; zr[1] = z1a; zr[2] = z2a; zr[3] = z3a; }
            else         { zr[0] = z0b; zr[1] = z1b; zr[2] = z2b; zr[3] = z3b; }
            #pragma unroll
            for (int r = 0; r < 4; r++) {
                float z = zr[r] + sc.x;
                float cvx = fmaf(z, a0.x, b0.x);
                cvx = fmaxf(cvx, fmaf(z, a0.y, b0.y));
                cvx = fmaxf(cvx, fmaf(z, a0.z, b0.z));
                cvx = fmaxf(cvx, fmaf(z, a0.w, b0.w));
                cvx = fmaxf(cvx, fmaf(z, a1.x, b1.x));
                cvx = fmaxf(cvx, fmaf(z, a1.y, b1.y));
                cvx = fmaxf(cvx, fmaf(z, a1.z, b1.z));
                cvx = fmaxf(cvx, fmaf(z, a1.w, b1.w));
                float ccv = fmaf(z, cc0.x, d0.x);
                ccv = fminf(ccv, fmaf(z, cc0.y, d0.y));
                ccv = fminf(ccv, fmaf(z, cc0.z, d0.z));
                ccv = fminf(ccv, fmaf(z, cc0.w, d0.w));
                ccv = fminf(ccv, fmaf(z, cc1.x, d1.x));
                ccv = fminf(ccv, fmaf(z, cc1.y, d1.y));
                ccv = fminf(ccv, fmaf(z, cc1.z, d1.z));
                ccv = fminf(ccv, fmaf(z, cc1.w, d1.w));
                float tv = sc.y * cvx + (1.0f - sc.y) * ccv;
                float cpre = accc[mi][ni][r] + sc.z;
                float gpre = accg[mi][ni][r] + sc.w;
                float g = sigm(gpre);
                float cla = gelu_f(cpre);
                int row = quad * 4 + r;
                // chunk (bits 3-4 of col) XOR quad: quads hit distinct 16B slots
                owave[row * 32 + ((ni * 16 + lr) ^ (quad << 3))] = f2bf(g * tv + (1.0f - g) * cla);
            }
        }
        // per-mi wave-local cooperative store (no cross-wave barrier needed)
        {
            int rl = lane >> 2, ch = lane & 3;
            ushort8 v = *(const ushort8*)&owave[rl * 32 + ((ch ^ (rl >> 2)) << 3)];
            *(ushort8*)&fused[(size_t)(bm * 128 + wm * 32 + mi * 16 + rl) * NF
                              + bfb * 64 + wf * 32 + ch * 8] = v;
        }
    }
}

// ------------------------------------------------- kernel 5: GEMM2 (fused@Wd + bd)
// BK=64, 16 K-iters. XCD swizzle: the 2 bn-siblings of a bm consecutive per XCD.
#define LDS2 64
__global__ __launch_bounds__(512, 4) void gemm2_kernel(
    const unsigned short* __restrict__ A,  // fused [T][1024]
    const unsigned short* __restrict__ Bt, // WdT [256][1024]
    const float* __restrict__ bd, float* __restrict__ out) {
    __shared__ __align__(16) unsigned short As[128 * LDS2];
    __shared__ __align__(16) unsigned short Bs[128 * LDS2];
    const int t = threadIdx.x;
    const int b = blockIdx.x;
    const int xcd = b & 7, j = b >> 3;
    const int bn = j & 1;
    const int bm = (j >> 1) * 8 + xcd;
    const int wave = t >> 6, lane = t & 63;
    const int wm = wave & 1, wn = wave >> 1;
    const int lr = lane & 15, quad = lane >> 4;
    const int srow = wave * 8 + (lane >> 3), scol = (lane & 7) << 3;  // 64 rows/issue
    const unsigned short* gA = A  + (size_t)(bm * 128 + srow) * NF + scol;
    const unsigned short* gB = Bt + (size_t)(bn * 128 + srow) * NF + scol;
    unsigned short* lA = &As[wave * 8 * LDS2];
    unsigned short* lB = &Bs[wave * 8 * LDS2];

    floatx4 acc[4][2];
    #pragma unroll
    for (int i = 0; i < 4; i++)
        #pragma unroll
        for (int jj = 0; jj < 2; jj++) acc[i][jj] = (floatx4)0.0f;

    for (int k0 = 0; k0 < NF; k0 += 64) {
        __syncthreads();
        g2lds16(gA + k0, lA);
        g2lds16(gA + k0 + (size_t)64 * NF, lA + 64 * LDS2);
        g2lds16(gB + k0, lB);
        g2lds16(gB + k0 + (size_t)64 * NF, lB + 64 * LDS2);
        __syncthreads();
        #pragma unroll
        for (int ks = 0; ks < 2; ks++) {
            bf16x8 af[4], bf_[2];
            #pragma unroll
            for (int mi = 0; mi < 4; mi++)
                af[mi] = *(const bf16x8*)&As[(wm * 64 + mi * 16 + lr) * LDS2 + ks * 32 + quad * 8];
            #pragma unroll
            for (int ni = 0; ni < 2; ni++)
                bf_[ni] = *(const bf16x8*)&Bs[(wn * 32 + ni * 16 + lr) * LDS2 + ks * 32 + quad * 8];
            #pragma unroll
            for (int mi = 0; mi < 4; mi++)
                #pragma unroll
                for (int ni = 0; ni < 2; ni++)
                    acc[mi][ni] = __builtin_amdgcn_mfma_f32_16x16x32_bf16(af[mi], bf_[ni], acc[mi][ni], 0, 0, 0);
        }
    }
    #pragma unroll
    for (int mi = 0; mi < 4; mi++)
        #pragma unroll
        for (int ni = 0; ni < 2; ni++) {
            int n = bn * 128 + wn * 32 + ni * 16 + lr;
            float bdv = bd[n];
            #pragma unroll
            for (int r = 0; r < 4; r++) {
                int m = bm * 128 + wm * 64 + mi * 16 + quad * 4 + r;
                out[m * DM + n] = acc[mi][ni][r] + bdv;
            }
        }
}

// ------------------------------------------------------------- launcher
extern "C" void kernel_launch(void* const* d_in, const int* in_sizes, int n_in,
                              void* d_out, int out_size, void* d_ws, size_t ws_size,
                              hipStream_t stream) {
    const float* x     = (const float*)d_in[0];
    const float* Wt    = (const float*)d_in[1];
    const float* bt    = (const float*)d_in[2];
    const float* slx   = (const float*)d_in[3];
    const float* ofx   = (const float*)d_in[4];
    const float* slc   = (const float*)d_in[5];
    const float* ofc   = (const float*)d_in[6];
    const float* alpha = (const float*)d_in[7];
    const float* Wc    = (const float*)d_in[8];
    const float* bc    = (const float*)d_in[9];
    const float* Wg    = (const float*)d_in[10];
    const float* bg    = (const float*)d_in[11];
    const float* Wd    = (const float*)d_in[12];
    const float* bd    = (const float*)d_in[13];
    float* out = (float*)d_out;
    char* ws = (char*)d_ws;

    unsigned int* slot = (unsigned int*)(ws + O_SLOT);
    float* s           = (float*)(ws + O_S);
    unsigned short* Wct = (unsigned short*)(ws + O_WCT);
    unsigned short* Wgt = (unsigned short*)(ws + O_WGT);
    unsigned short* WdT = (unsigned short*)(ws + O_WDT);
    float* WtT          = (float*)(ws + O_WTT);
    unsigned short* xbf = (unsigned short*)(ws + O_XBF);
    int* counts         = (int*)(ws + O_CNT);
    int* cidx           = (int*)(ws + O_CIDX);
    float* cval         = (float*)(ws + O_CVAL);
    unsigned short* fused = (unsigned short*)(ws + O_FUSD);

    pack_kernel<<<1024, 256, 0, stream>>>(Wt, alpha, Wc, Wg, Wd, Wct, Wgt, WdT, WtT, s, slot);
    minmax_kernel<<<128, 256, 0, stream>>>(Wt, slot);
    cand_kernel<<<TTOK, 256, 0, stream>>>(x, slot, xbf, counts, cidx, cval);
    gemm1_kernel<<<4096, 512, 0, stream>>>(
        xbf, Wct, Wgt, bc, bg, counts, cidx, cval, x, WtT, bt,
        slx, ofx, slc, ofc, s, fused);
    gemm2_kernel<<<512, 512, 0, stream>>>(fused, WdT, bd, out);
}

// Round 2
// 328.497 us; speedup vs baseline: 1.5076x; 1.5076x over previous
//
#include <hip/hip_runtime.h>

// ---------------------------------------------------------------- constants
#define TTOK 32768
#define DM   256
#define NF   1024
#define KMAX 32

typedef __attribute__((ext_vector_type(8))) unsigned short ushort8;
typedef __attribute__((ext_vector_type(8))) __bf16 bf16x8;
typedef __attribute__((ext_vector_type(4))) float floatx4;

// workspace offsets (all 256B aligned)
constexpr size_t O_SLOT = 0;                                   // 1 uint (max|Wt|)
constexpr size_t O_S    = 256;                                 // 1024 f32 sigmoid(alpha)
constexpr size_t O_WCT  = O_S    + 4096;                       // Wc^T  [1024][256] bf16
constexpr size_t O_WGT  = O_WCT  + (size_t)NF*DM*2;            // Wg^T  [1024][256] bf16
constexpr size_t O_WDT  = O_WGT  + (size_t)NF*DM*2;            // Wd^T  [256][1024] bf16
constexpr size_t O_WTT  = O_WDT  + (size_t)DM*NF*2;            // Wt^T  [256][1024] f32
constexpr size_t O_XBF  = O_WTT  + (size_t)DM*NF*4;            // x bf16 [T][256]
constexpr size_t O_CNT  = O_XBF  + (size_t)TTOK*DM*2;          // counts [T]
constexpr size_t O_CIDX = O_CNT  + (size_t)TTOK*4;             // cand d (raw) [T][KMAX]
constexpr size_t O_CVAL = O_CIDX + (size_t)TTOK*KMAX*4;        // cand val [T][KMAX]
constexpr size_t O_FUSD = O_CVAL + (size_t)TTOK*KMAX*4;        // fused bf16 [T][1024]

__device__ __forceinline__ float bf2f(unsigned short u) {
    union { unsigned int i; float f; } c; c.i = ((unsigned int)u) << 16; return c.f;
}
__device__ __forceinline__ unsigned short f2bf(float v) {
    union { float f; unsigned int i; } c; c.f = v;
    unsigned int b = c.i;
    return (unsigned short)((b + 0x7FFFu + ((b >> 16) & 1u)) >> 16);
}
__device__ __forceinline__ float sigm(float z) { return 1.0f / (1.0f + __expf(-z)); }
// tanh-gelu: max |diff| vs exact erf-gelu ~3e-3, far under tolerance
__device__ __forceinline__ float gelu_f(float x) {
    return x * sigm(1.59576912f * (x + 0.044715f * x * x * x));
}
// async global->LDS, 16B per lane; lds dest = wave-uniform base + lane*16 [m97/m104]
__device__ __forceinline__ void g2lds16(const unsigned short* g, unsigned short* l) {
    __builtin_amdgcn_global_load_lds((const __attribute__((address_space(1))) unsigned int*)g,
                                     (__attribute__((address_space(3))) unsigned int*)l, 16, 0, 0);
}

// ------------------------------------------------- kernel 1: pack weights
__global__ void pack_kernel(const float* __restrict__ Wt, const float* __restrict__ alpha,
                            const float* __restrict__ Wc, const float* __restrict__ Wg,
                            const float* __restrict__ Wd,
                            unsigned short* __restrict__ Wct, unsigned short* __restrict__ Wgt,
                            unsigned short* __restrict__ WdT, float* __restrict__ WtT,
                            float* __restrict__ s, unsigned int* __restrict__ slot) {
    int e = blockIdx.x * 256 + threadIdx.x;
    if (e == 0) *slot = 0u;
    { int f = e >> 8, k = e & 255;           // Wc/Wg are [256][1024]
      Wct[e] = f2bf(Wc[k * NF + f]);
      Wgt[e] = f2bf(Wg[k * NF + f]); }
    { int n = e >> 10, k = e & 1023;         // Wd is [1024][256]
      WdT[e] = f2bf(Wd[k * DM + n]); }
    { int d = e >> 10, f = e & 1023;         // Wt is [1024][256]
      WtT[e] = Wt[f * DM + d]; }
    if (e < NF) s[e] = sigm(alpha[e]);
}

// ------------------------------------------------- kernel 2: max|Wt| reduce
__global__ void minmax_kernel(const float* __restrict__ Wt, unsigned int* __restrict__ slot) {
    int g = blockIdx.x * 256 + threadIdx.x;
    float lm = 0.0f;
    for (int i = g; i < NF * DM; i += 128 * 256) lm = fmaxf(lm, fabsf(Wt[i]));
    #pragma unroll
    for (int o = 32; o > 0; o >>= 1) lm = fmaxf(lm, __shfl_xor(lm, o));
    if ((threadIdx.x & 63) == 0) atomicMax(slot, __float_as_uint(lm)); // |w|>=0: uint order ok
}

// ------------------------------------------------- kernel 3: candidates + x->bf16
// r8 rewrite: wave-per-token (was block-per-token: 32768 blocks + LDS atomics).
// 8192 blocks x 4 waves; lane l owns d = l, l+64, l+128, l+192.
// Compaction via ballot+prefix-popcount; direct global writes (no LDS, no atomics).
// Candidate order differs from before -- max is commutative, order irrelevant.
__global__ __launch_bounds__(256) void cand_kernel(
        const float* __restrict__ x, const unsigned int* __restrict__ slot,
        unsigned short* __restrict__ xbf, int* __restrict__ counts,
        int* __restrict__ cidx, float* __restrict__ cval) {
    const int wave = threadIdx.x >> 6, lane = threadIdx.x & 63;
    const int tok = blockIdx.x * 4 + wave;
    const float* xr = x + (size_t)tok * DM;
    float v0 = xr[lane], v1 = xr[lane + 64], v2 = xr[lane + 128], v3 = xr[lane + 192];
    unsigned short* xo = xbf + (size_t)tok * DM;
    xo[lane]       = f2bf(v0);
    xo[lane + 64]  = f2bf(v1);
    xo[lane + 128] = f2bf(v2);
    xo[lane + 192] = f2bf(v3);
    float m = fmaxf(fmaxf(v0, v1), fmaxf(v2, v3));
    #pragma unroll
    for (int o = 32; o > 0; o >>= 1) m = fmaxf(m, __shfl_xor(m, o));
    const float delta = 2.0f * __uint_as_float(*slot);  // >= Wmax-Wmin: exact exclusion bound
    const float thr = m - delta;
    const unsigned long long lt = (lane == 63) ? 0x7FFFFFFFFFFFFFFFull
                                               : ((1ull << lane) - 1ull);
    float vv[4] = { v0, v1, v2, v3 };
    int base = 0;
    #pragma unroll
    for (int j = 0; j < 4; j++) {
        bool p = vv[j] >= thr;
        unsigned long long mask = __ballot(p);
        int pos = base + __popcll(mask & lt);
        if (p && pos < KMAX) {
            cidx[(size_t)tok * KMAX + pos] = lane + j * 64;
            cval[(size_t)tok * KMAX + pos] = vv[j];
        }
        base += __popcll(mask);
    }
    if (lane == 0) counts[tok] = base;
}

// ------------------------------------------------- kernel 4: fused GEMM1
// (x@Wc, x@Wg) MFMA + tropical max-plus + convex/concave + gate blend.
// 128x128 tile, BK=32, 512 thr (8 waves 2Mx4F, wave 64x32 dual-output).
// r7 lesson (REVERTED): 128x64 tile + (512,6) reg bound -> spills (WRITE +230MB)
//   + L2 thrash (FETCH 29->200MB) + occupancy unchanged. 128x128 dual-GEMM is
//   structurally 2 blocks/CU (acc 64 f32 + frags = 128 unified regs = 4 w/SIMD;
//   LDS caps identically). Keep it; attack the per-iter stalls instead.
// r8 changes on the r6 base:
//  - Double-buffered staging (2x24KB), ONE __syncthreads per K-step; stage k+1
//    issued before compute k (T3-minimum 2-phase) -- was 2 full drains/step
//    with staging never overlapped.
//  - par/sOV/sCnt prestaged at kernel start into dedicated regions (published
//    by the first loop barrier) -- removes the post-loop serial staging stall.
//  - sOV KCAP=16 (exact 256-d fallback covers count>16; P ~ 1e-9) funds the
//    second stage buffer. Total LDS exactly 76800B -> 2 blocks/CU unchanged.
//  - obuf overlays dead staging buffers post-loop (safe: writes only after the
//    final in-loop barrier).
// NOT chased: SQ_LDS_BANK_CONFLICT 4.7M -- the wave's af/bf ds_read_b128 covers
// a dense contiguous 1KB (16 rows x 64B); density-optimal, swizzle can't help.
#define LDSS  32     // ushorts per LDS row, no pad (wave-uniform-base DMA, m104)
#define KCAP  16
#define KPADL 17
#define OSTR  136    // obuf row stride in ushorts (272B, 16q+4r+col bank spread)
#define STAGEB 24576 // bytes per stage buffer (As 8K | Bcs 8K | Bgs 8K)
__global__ __launch_bounds__(512, 4) void gemm1_kernel(
    const unsigned short* __restrict__ A,   // xbf [T][256]
    const unsigned short* __restrict__ Bct, // [1024][256]
    const unsigned short* __restrict__ Bgt, // [1024][256]
    const float* __restrict__ bc, const float* __restrict__ bg,
    const int* __restrict__ counts, const int* __restrict__ cidx,
    const float* __restrict__ cval, const float* __restrict__ x,
    const float* __restrict__ WtT, const float* __restrict__ bt,
    const float* __restrict__ slx, const float* __restrict__ ofx,
    const float* __restrict__ slc, const float* __restrict__ ofc,
    const float* __restrict__ s, unsigned short* __restrict__ fused) {
    __shared__ __align__(16) char smem[76800];
    // [0,24576) stage buf0 ; [24576,49152) stage buf1
    unsigned short* obuf = (unsigned short*)smem;       // post-loop overlay [0,34816)
    float* par = (float*)(smem + 49152);                // [49152,67584) 128 x 36 f32
    int* sOV  = (int*)(smem + 67584);                   // [67584,76288) 128 x KPADL
    int* sCnt = (int*)(smem + 76288);                   // [76288,76800)
    const int t = threadIdx.x;
    // XCD-aware swizzle: 8 bf-siblings of a bm consecutive within one XCD's
    // stream -> A-tile + meta L2-hot (r6 lesson; FETCH 29MB confirms)
    const int b = blockIdx.x;
    const int xcd = b & 7, j = b >> 3;
    const int bf = j & 7;
    const int bm = (j >> 3) * 8 + xcd;
    const int wave = t >> 6, lane = t & 63;
    const int wm = wave & 1, wn = wave >> 1;
    const int lr = lane & 15, quad = lane >> 4;
    const int srow = wave * 16 + (lane >> 2), scol = (lane & 3) << 3;
    const unsigned short* gA = A   + (size_t)(bm * 128 + srow) * DM + scol;
    const unsigned short* gC = Bct + (size_t)(bf * 128 + srow) * DM + scol;
    const unsigned short* gG = Bgt + (size_t)(bf * 128 + srow) * DM + scol;
    const int lofs = wave * 16 * LDSS;  // per-wave staging dest offset (ushorts)

    // ---- prestage meta + epilogue params (dedicated regions; first loop
    //      barrier publishes; loads overlap the K-loop prologue)
    if (t < 128) sCnt[t] = counts[bm * 128 + t];
    const int PADV = (int)(((unsigned int)f2bf(-1e30f)) << 16);
    #pragma unroll
    for (int e = t; e < 2048; e += 512) {
        int m = e >> 4, k = e & 15;
        int c = counts[bm * 128 + m];
        int pk = PADV;
        if (k < (c < KCAP ? c : KCAP)) {
            int d  = cidx[(size_t)(bm * 128 + m) * KMAX + k];
            float v = cval[(size_t)(bm * 128 + m) * KMAX + k];
            pk = (int)(((unsigned int)f2bf(v)) << 16) | d;
        }
        sOV[m * KPADL + k] = pk;
    }
    // par[fl*36 + {0..7 slx, 8..15 ofx, 16..23 slc, 24..31 ofc, 32 bt, 33 s, 34 bc, 35 bg}]
    #pragma unroll
    for (int e = t; e < 1024; e += 512) {
        int ff = e >> 3, w = e & 7;
        int gf = (bf * 128 + ff) * 8 + w;
        par[ff * 36 + w]      = slx[gf];
        par[ff * 36 + 8 + w]  = ofx[gf];
        par[ff * 36 + 16 + w] = slc[gf];
        par[ff * 36 + 24 + w] = ofc[gf];
    }
    if (t < 128) {
        int gf = bf * 128 + t;
        par[t * 36 + 32] = bt[gf];
        par[t * 36 + 33] = s[gf];
        par[t * 36 + 34] = bc[gf];
        par[t * 36 + 35] = bg[gf];
    }

    floatx4 accc[4][2], accg[4][2];
    #pragma unroll
    for (int i = 0; i < 4; i++)
        #pragma unroll
        for (int jj = 0; jj < 2; jj++) { accc[i][jj] = (floatx4)0.0f; accg[i][jj] = (floatx4)0.0f; }

    // ---- K-loop: double-buffered, one barrier per step ----
    {
        unsigned short* b0 = (unsigned short*)smem;
        g2lds16(gA, b0 + lofs);
        g2lds16(gC, b0 + 4096 + lofs);
        g2lds16(gG, b0 + 8192 + lofs);
    }
    __syncthreads();   // publishes stage0 + sOV/sCnt/par
    #pragma unroll
    for (int k = 0; k < 8; k++) {
        unsigned short* cur = (unsigned short*)(smem + (size_t)(k & 1) * STAGEB);
        if (k < 7) {
            unsigned short* nxt = (unsigned short*)(smem + (size_t)((k + 1) & 1) * STAGEB);
            int k0 = (k + 1) * 32;
            g2lds16(gA + k0, nxt + lofs);
            g2lds16(gC + k0, nxt + 4096 + lofs);
            g2lds16(gG + k0, nxt + 8192 + lofs);
        }
        bf16x8 af[4], bcf[2], bgf[2];
        #pragma unroll
        for (int mi = 0; mi < 4; mi++)
            af[mi] = *(const bf16x8*)&cur[(wm * 64 + mi * 16 + lr) * LDSS + quad * 8];
        #pragma unroll
        for (int ni = 0; ni < 2; ni++) {
            bcf[ni] = *(const bf16x8*)&cur[4096 + (wn * 32 + ni * 16 + lr) * LDSS + quad * 8];
            bgf[ni] = *(const bf16x8*)&cur[8192 + (wn * 32 + ni * 16 + lr) * LDSS + quad * 8];
        }
        #pragma unroll
        for (int mi = 0; mi < 4; mi++)
            #pragma unroll
            for (int ni = 0; ni < 2; ni++) {
                accc[mi][ni] = __builtin_amdgcn_mfma_f32_16x16x32_bf16(af[mi], bcf[ni], accc[mi][ni], 0, 0, 0);
                accg[mi][ni] = __builtin_amdgcn_mfma_f32_16x16x32_bf16(af[mi], bgf[ni], accg[mi][ni], 0, 0, 0);
            }
        __syncthreads();   // stage k+1 complete; all reads of cur done -> reusable
    }
    // staging buffers dead from here; obuf overlays them.

    // ---- fused epilogue: tropical z + convex/concave + gate blend ----
    // C/D layout col=lane&15, row=quad*4+r  [verified m89/m91]
    const int f0 = bf * 128 + wn * 32 + lr;    // ni=0 global f; ni=1 is +16
    #pragma unroll
    for (int mi = 0; mi < 4; mi++) {
        const int mb = wm * 64 + mi * 16 + quad * 4;   // local m of r=0
        int c0 = sCnt[mb], c1 = sCnt[mb + 1], c2 = sCnt[mb + 2], c3 = sCnt[mb + 3];
        int k0c = c0 < KCAP ? c0 : KCAP, k1c = c1 < KCAP ? c1 : KCAP;
        int k2c = c2 < KCAP ? c2 : KCAP, k3c = c3 < KCAP ? c3 : KCAP;
        int km = max(max(k0c, k1c), max(k2c, k3c));
        float z0a = -1e30f, z1a = -1e30f, z2a = -1e30f, z3a = -1e30f;  // ni=0
        float z0b = -1e30f, z1b = -1e30f, z2b = -1e30f, z3b = -1e30f;  // ni=1
        for (int k = 0; k < km; k++) {
            int p0 = sOV[(mb + 0) * KPADL + k];
            int p1 = sOV[(mb + 1) * KPADL + k];
            int p2 = sOV[(mb + 2) * KPADL + k];
            int p3 = sOV[(mb + 3) * KPADL + k];
            const float* r0 = WtT + ((p0 & 0xFFFF) << 10) + f0;
            const float* r1 = WtT + ((p1 & 0xFFFF) << 10) + f0;
            const float* r2 = WtT + ((p2 & 0xFFFF) << 10) + f0;
            const float* r3 = WtT + ((p3 & 0xFFFF) << 10) + f0;
            float w0a = r0[0], w0b = r0[16];
            float w1a = r1[0], w1b = r1[16];
            float w2a = r2[0], w2b = r2[16];
            float w3a = r3[0], w3b = r3[16];
            float v0 = __int_as_float(p0 & 0xFFFF0000);
            float v1 = __int_as_float(p1 & 0xFFFF0000);
            float v2 = __int_as_float(p2 & 0xFFFF0000);
            float v3 = __int_as_float(p3 & 0xFFFF0000);
            z0a = fmaxf(z0a, v0 + w0a); z0b = fmaxf(z0b, v0 + w0b);
            z1a = fmaxf(z1a, v1 + w1a); z1b = fmaxf(z1b, v1 + w1b);
            z2a = fmaxf(z2a, v2 + w2a); z2b = fmaxf(z2b, v2 + w2b);
            z3a = fmaxf(z3a, v3 + w3a); z3b = fmaxf(z3b, v3 + w3b);
        }
        // exact fallback (count > KCAP, ~never): full 256-d scan
        if (c0 > KCAP || c1 > KCAP || c2 > KCAP || c3 > KCAP) {
            float za[4] = { z0a, z1a, z2a, z3a };
            float zb[4] = { z0b, z1b, z2b, z3b };
            int cc[4] = { c0, c1, c2, c3 };
            #pragma unroll 1
            for (int r = 0; r < 4; r++) if (cc[r] > KCAP) {
                const float* xr = x + (size_t)(bm * 128 + mb + r) * DM;
                float ma = -1e30f, mbv = -1e30f;
                for (int d = 0; d < DM; d++) {
                    float xv = xr[d];
                    ma  = fmaxf(ma,  xv + WtT[d * NF + f0]);
                    mbv = fmaxf(mbv, xv + WtT[d * NF + f0 + 16]);
                }
                za[r] = ma; zb[r] = mbv;
            }
            z0a = za[0]; z1a = za[1]; z2a = za[2]; z3a = za[3];
            z0b = zb[0]; z1b = zb[1]; z2b = zb[2]; z3b = zb[3];
        }
        #pragma unroll
        for (int ni = 0; ni < 2; ni++) {
            const int fl = wn * 32 + ni * 16 + lr;
            const float* pp = par + fl * 36;
            float4 a0 = *(const float4*)(pp),      a1 = *(const float4*)(pp + 4);
            float4 b0 = *(const float4*)(pp + 8),  b1 = *(const float4*)(pp + 12);
            float4 cc0 = *(const float4*)(pp + 16), cc1 = *(const float4*)(pp + 20);
            float4 d0 = *(const float4*)(pp + 24), d1 = *(const float4*)(pp + 28);
            float4 sc = *(const float4*)(pp + 32);  // bt, s, bc, bg
            float zr[4];
            if (ni == 0) { zr[0] = z0a; zr[1] = z1a; zr[2] = z2a; zr[3] = z3a; }
            else         { zr[0] = z0b; zr[1] = z1b; zr[2] = z2b; zr[3] = z3b; }
            #pragma unroll
            for (int r = 0; r < 4; r++) {
                float z = zr[r] + sc.x;
                float cvx = fmaf(z, a0.x, b0.x);
                cvx = fmaxf(cvx, fmaf(z, a0.y, b0.y));
                cvx = fmaxf(cvx, fmaf(z, a0.z, b0.z));
                cvx = fmaxf(cvx, fmaf(z, a0.w, b0.w));
                cvx = fmaxf(cvx, fmaf(z, a1.x, b1.x));
                cvx = fmaxf(cvx, fmaf(z, a1.y, b1.y));
                cvx = fmaxf(cvx, fmaf(z, a1.z, b1.z));
                cvx = fmaxf(cvx, fmaf(z, a1.w, b1.w));
                float ccv = fmaf(z, cc0.x, d0.x);
                ccv = fminf(ccv, fmaf(z, cc0.y, d0.y));
                ccv = fminf(ccv, fmaf(z, cc0.z, d0.z));
                ccv = fminf(ccv, fmaf(z, cc0.w, d0.w));
                ccv = fminf(ccv, fmaf(z, cc1.x, d1.x));
                ccv = fminf(ccv, fmaf(z, cc1.y, d1.y));
                ccv = fminf(ccv, fmaf(z, cc1.z, d1.z));
                ccv = fminf(ccv, fmaf(z, cc1.w, d1.w));
                float tv = sc.y * cvx + (1.0f - sc.y) * ccv;
                float cpre = accc[mi][ni][r] + sc.z;
                float gpre = accg[mi][ni][r] + sc.w;
                float g = sigm(gpre);
                float cla = gelu_f(cpre);
                obuf[(mb + r) * OSTR + fl] = f2bf(g * tv + (1.0f - g) * cla);
            }
        }
    }
    __syncthreads();   // full 128x128 obuf tile complete
    // cooperative coalesced store: 256B contiguous per row-segment
    #pragma unroll
    for (int e = t; e < 128 * 16; e += 512) {
        int row = e >> 4, c8 = (e & 15) << 3;
        ushort8 v = *(const ushort8*)&obuf[row * OSTR + c8];
        *(ushort8*)&fused[(size_t)(bm * 128 + row) * NF + bf * 128 + c8] = v;
    }
}

// ------------------------------------------------- kernel 5: GEMM2 (fused@Wd + bd)
// BK=64, 16 K-iters. XCD swizzle: the 2 bn-siblings of a bm consecutive per XCD.
#define LDS2 64
__global__ __launch_bounds__(512, 4) void gemm2_kernel(
    const unsigned short* __restrict__ A,  // fused [T][1024]
    const unsigned short* __restrict__ Bt, // WdT [256][1024]
    const float* __restrict__ bd, float* __restrict__ out) {
    __shared__ __align__(16) unsigned short As[128 * LDS2];
    __shared__ __align__(16) unsigned short Bs[128 * LDS2];
    const int t = threadIdx.x;
    const int b = blockIdx.x;
    const int xcd = b & 7, j = b >> 3;
    const int bn = j & 1;
    const int bm = (j >> 1) * 8 + xcd;
    const int wave = t >> 6, lane = t & 63;
    const int wm = wave & 1, wn = wave >> 1;
    const int lr = lane & 15, quad = lane >> 4;
    const int srow = wave * 8 + (lane >> 3), scol = (lane & 7) << 3;  // 64 rows/issue
    const unsigned short* gA = A  + (size_t)(bm * 128 + srow) * NF + scol;
    const unsigned short* gB = Bt + (size_t)(bn * 128 + srow) * NF + scol;
    unsigned short* lA = &As[wave * 8 * LDS2];
    unsigned short* lB = &Bs[wave * 8 * LDS2];

    floatx4 acc[4][2];
    #pragma unroll
    for (int i = 0; i < 4; i++)
        #pragma unroll
        for (int jj = 0; jj < 2; jj++) acc[i][jj] = (floatx4)0.0f;

    for (int k0 = 0; k0 < NF; k0 += 64) {
        __syncthreads();
        g2lds16(gA + k0, lA);
        g2lds16(gA + k0 + (size_t)64 * NF, lA + 64 * LDS2);
        g2lds16(gB + k0, lB);
        g2lds16(gB + k0 + (size_t)64 * NF, lB + 64 * LDS2);
        __syncthreads();
        #pragma unroll
        for (int ks = 0; ks < 2; ks++) {
            bf16x8 af[4], bf_[2];
            #pragma unroll
            for (int mi = 0; mi < 4; mi++)
                af[mi] = *(const bf16x8*)&As[(wm * 64 + mi * 16 + lr) * LDS2 + ks * 32 + quad * 8];
            #pragma unroll
            for (int ni = 0; ni < 2; ni++)
                bf_[ni] = *(const bf16x8*)&Bs[(wn * 32 + ni * 16 + lr) * LDS2 + ks * 32 + quad * 8];
            #pragma unroll
            for (int mi = 0; mi < 4; mi++)
                #pragma unroll
                for (int ni = 0; ni < 2; ni++)
                    acc[mi][ni] = __builtin_amdgcn_mfma_f32_16x16x32_bf16(af[mi], bf_[ni], acc[mi][ni], 0, 0, 0);
        }
    }
    #pragma unroll
    for (int mi = 0; mi < 4; mi++)
        #pragma unroll
        for (int ni = 0; ni < 2; ni++) {
            int n = bn * 128 + wn * 32 + ni * 16 + lr;
            float bdv = bd[n];
            #pragma unroll
            for (int r = 0; r < 4; r++) {
                int m = bm * 128 + wm * 64 + mi * 16 + quad * 4 + r;
                out[m * DM + n] = acc[mi][ni][r] + bdv;
            }
        }
}

// ------------------------------------------------------------- launcher
extern "C" void kernel_launch(void* const* d_in, const int* in_sizes, int n_in,
                              void* d_out, int out_size, void* d_ws, size_t ws_size,
                              hipStream_t stream) {
    const float* x     = (const float*)d_in[0];
    const float* Wt    = (const float*)d_in[1];
    const float* bt    = (const float*)d_in[2];
    const float* slx   = (const float*)d_in[3];
    const float* ofx   = (const float*)d_in[4];
    const float* slc   = (const float*)d_in[5];
    const float* ofc   = (const float*)d_in[6];
    const float* alpha = (const float*)d_in[7];
    const float* Wc    = (const float*)d_in[8];
    const float* bc    = (const float*)d_in[9];
    const float* Wg    = (const float*)d_in[10];
    const float* bg    = (const float*)d_in[11];
    const float* Wd    = (const float*)d_in[12];
    const float* bd    = (const float*)d_in[13];
    float* out = (float*)d_out;
    char* ws = (char*)d_ws;

    unsigned int* slot = (unsigned int*)(ws + O_SLOT);
    float* s           = (float*)(ws + O_S);
    unsigned short* Wct = (unsigned short*)(ws + O_WCT);
    unsigned short* Wgt = (unsigned short*)(ws + O_WGT);
    unsigned short* WdT = (unsigned short*)(ws + O_WDT);
    float* WtT          = (float*)(ws + O_WTT);
    unsigned short* xbf = (unsigned short*)(ws + O_XBF);
    int* counts         = (int*)(ws + O_CNT);
    int* cidx           = (int*)(ws + O_CIDX);
    float* cval         = (float*)(ws + O_CVAL);
    unsigned short* fused = (unsigned short*)(ws + O_FUSD);

    pack_kernel<<<1024, 256, 0, stream>>>(Wt, alpha, Wc, Wg, Wd, Wct, Wgt, WdT, WtT, s, slot);
    minmax_kernel<<<128, 256, 0, stream>>>(Wt, slot);
    cand_kernel<<<TTOK / 4, 256, 0, stream>>>(x, slot, xbf, counts, cidx, cval);
    gemm1_kernel<<<2048, 512, 0, stream>>>(
        xbf, Wct, Wgt, bc, bg, counts, cidx, cval, x, WtT, bt,
        slx, ofx, slc, ofc, s, fused);
    gemm2_kernel<<<512, 512, 0, stream>>>(fused, WdT, bd, out);
}